// Round 6
// baseline (658.034 us; speedup 1.0000x reference)
//
#include <hip/hip_runtime.h>
#include <hip/hip_bf16.h>

#define HID 128
#define ISZ 75
#define GATES 512
#define TT 512
#define BB 512

typedef _Float16 half8 __attribute__((ext_vector_type(8)));
typedef _Float16 half4 __attribute__((ext_vector_type(4)));
typedef float floatx4 __attribute__((ext_vector_type(4)));

__device__ __forceinline__ float rcp_fast(float x) { return __builtin_amdgcn_rcpf(x); }
__device__ __forceinline__ float sigmoid_f(float x) { return rcp_fast(1.f + __expf(-x)); }
__device__ __forceinline__ float tanh_f(float x) { return 1.f - 2.f * rcp_fast(__expf(2.f * x) + 1.f); }

// ============================================================================
// Phase 1: xg[b*T+t][g] = x[b,t,:] @ w_ih[g,:] + b_ih[g] + b_hh[g]   (f16 out)
// M = B*T = 262144 rows, N = 512 gates, K = 75 (pad 96). 512 blocks x 256 thr
// (4 waves), 512 rows/block, 2 n-halves of 256 gates. ~67 KB LDS -> 2 blk/CU.
// Fragment convention (verified in round 4): A[m][k]: m=l15, k=l4*8+e;
// B[k][n]: n=l15, k=l4*8+e; D[m][n]: n=l15, m=l4*4+j.
// ============================================================================
__global__ __launch_bounds__(256, 2) void xg_gemm(
    const float* __restrict__ x,      // [B*T, 75]
    const float* __restrict__ w_ih,   // [512, 75]
    const float* __restrict__ b_ih,   // [512]
    const float* __restrict__ b_hh,   // [512]
    _Float16* __restrict__ xg)        // [B*T, 512]
{
    const int tid = threadIdx.x;
    const int wv = tid >> 6, lane = tid & 63;
    const int l15 = lane & 15, l4 = lane >> 4;

    // w chunk layout: 16B chunk index (k>>3)*256 + g' ; conflict-free b128 reads
    __shared__ __align__(16) _Float16 wlds[12 * 256 * 8];   // 48 KB
    __shared__ __align__(16) float    xlds[64 * ISZ];       // 18.75 KB

    const size_t rowblk = (size_t)blockIdx.x * 512;

    for (int nh = 0; nh < 2; ++nh) {
        const int gbase = nh * 256;
        // ---- stage w_ih half -> wlds (f16, k-chunk-major) ----
        {
            const float* wrow = w_ih + (size_t)(gbase + tid) * ISZ;
            for (int k = 0; k < 96; ++k) {
                float v = (k < ISZ) ? wrow[k] : 0.f;
                wlds[((k >> 3) * 256 + tid) * 8 + (k & 7)] = (_Float16)v;
            }
        }
        float biasv[16];
#pragma unroll
        for (int nt = 0; nt < 16; ++nt) {
            int g = gbase + nt * 16 + l15;
            biasv[nt] = b_ih[g] + b_hh[g];
        }
        __syncthreads();

        for (int mt = 0; mt < 8; ++mt) {
            const size_t r0 = rowblk + (size_t)mt * 64;
            // ---- stage 64 x-rows (contiguous 19200 B) ----
            {
                const float4* src = (const float4*)(x + r0 * ISZ);
                float4* dst = (float4*)xlds;
                for (int i = tid; i < 1200; i += 256) dst[i] = src[i];
            }
            __syncthreads();

            // A fragments: this wave's 16 rows
            half8 af[3];
#pragma unroll
            for (int kc = 0; kc < 3; ++kc) {
                const int rb = (wv * 16 + l15) * ISZ;
                half8 f;
#pragma unroll
                for (int e = 0; e < 8; ++e) {
                    int k = kc * 32 + l4 * 8 + e;
                    int kk = (k < ISZ) ? k : 0;
                    float v = xlds[rb + kk];
                    f[e] = (_Float16)((k < ISZ) ? v : 0.f);
                }
                af[kc] = f;
            }

            floatx4 acc[16];
#pragma unroll
            for (int nt = 0; nt < 16; ++nt)
                acc[nt] = (floatx4){biasv[nt], biasv[nt], biasv[nt], biasv[nt]};
#pragma unroll
            for (int kc = 0; kc < 3; ++kc) {
                const int cb = (kc * 4 + l4) * 256;
#pragma unroll
                for (int nt = 0; nt < 16; ++nt) {
                    half8 bf = *(const half8*)&wlds[(cb + nt * 16 + l15) * 8];
                    acc[nt] = __builtin_amdgcn_mfma_f32_16x16x32_f16(af[kc], bf, acc[nt], 0, 0, 0);
                }
            }

            // direct f16 stores: row = r0 + wv*16 + l4*4 + j, col = gbase + nt*16 + l15
            _Float16* orow = xg + (r0 + wv * 16 + l4 * 4) * GATES + gbase + l15;
#pragma unroll
            for (int nt = 0; nt < 16; ++nt) {
#pragma unroll
                for (int j = 0; j < 4; ++j)
                    orow[(size_t)j * GATES + nt * 16] = (_Float16)acc[nt][j];
            }
            __syncthreads();   // xlds safe to restage
        }
        __syncthreads();       // wlds safe to restage
    }
}

// ============================================================================
// Phase 2: recurrence. 256 blocks (1/CU) x 1024 thr (16 waves), 2 batch rows
// per block. Per step: P[512g x 16n(2 real)] = W_hh[512x128] @ h^T, acc init
// from precomputed xg. h stored k-major in LDS (conflict-free b128 reads).
// ============================================================================
__global__ __launch_bounds__(1024, 1) void lstm_rec(
    const _Float16* __restrict__ xg,  // [B*T, 512] pre-activation (bias folded)
    const float* __restrict__ w_hh,   // [512, 128]
    const float* __restrict__ fc_w,   // [10, 128]
    const float* __restrict__ fc_b,   // [10]
    float* __restrict__ out)          // [B, 10]
{
    const int tid = threadIdx.x;
    const int wave = tid >> 6, lane = tid & 63;
    const int l15 = lane & 15, l4 = lane >> 4;
    const int b0 = blockIdx.x * 2;
    const int wb = wave * 32;

    // h k-major: f16 at ((k>>3)*16 + row)*8 + (k&7); rows 2..15 stay zero
    __shared__ __align__(16) _Float16 zsh[16 * 16 * 8];   // 4 KB
    __shared__ __align__(16) float    psh[2][GATES];      // 4 KB

    // persistent W_hh fragments: wave owns gates [wb, wb+32)
    half8 wfr[2][4];
#pragma unroll
    for (int mt = 0; mt < 2; ++mt) {
        const int R = wb + mt * 16 + l15;
#pragma unroll
        for (int kc = 0; kc < 4; ++kc) {
            half8 f;
#pragma unroll
            for (int e = 0; e < 8; ++e)
                f[e] = (_Float16)w_hh[R * HID + kc * 32 + l4 * 8 + e];
            wfr[mt][kc] = f;
        }
    }
    for (int i = tid; i < 16 * 16 * 8 / 2; i += 1024) ((uint32_t*)zsh)[i] = 0;

    float c = 0.f;
    const bool ldact = (l15 < 2);
    // per-lane xg pointer for batch row b0+l15 (valid addr for all lanes)
    const _Float16* xgp = xg + ((size_t)(b0 + (l15 & 1)) * TT) * GATES + wb + l4 * 4;

    half4 xgA0, xgA1, xgB0, xgB1;
    if (ldact) {
        xgA0 = *(const half4*)(xgp);
        xgA1 = *(const half4*)(xgp + 16);
        xgB0 = *(const half4*)(xgp + GATES);
        xgB1 = *(const half4*)(xgp + GATES + 16);
    }
    __syncthreads();

    auto step = [&](half4& xq0, half4& xq1, int tpre) {
        floatx4 acc0, acc1;
#pragma unroll
        for (int j = 0; j < 4; ++j) { acc0[j] = (float)xq0[j]; acc1[j] = (float)xq1[j]; }
        if (ldact) {   // depth-2 prefetch: issue now, consumed 2 steps later
            const _Float16* p = xgp + (size_t)tpre * GATES;
            xq0 = *(const half4*)(p);
            xq1 = *(const half4*)(p + 16);
        }
#pragma unroll
        for (int kc = 0; kc < 4; ++kc) {
            half8 z = *(const half8*)&zsh[((kc * 4 + l4) * 16 + l15) * 8];
            acc0 = __builtin_amdgcn_mfma_f32_16x16x32_f16(wfr[0][kc], z, acc0, 0, 0, 0);
            acc1 = __builtin_amdgcn_mfma_f32_16x16x32_f16(wfr[1][kc], z, acc1, 0, 0, 0);
        }
        if (ldact) {
            *(floatx4*)&psh[l15][wb + l4 * 4]      = acc0;
            *(floatx4*)&psh[l15][wb + 16 + l4 * 4] = acc1;
        }
        __syncthreads();
        if (tid < 256) {
            const int nb = tid >> 7, j = tid & 127;
            float ig = sigmoid_f(psh[nb][j]);
            float fg = sigmoid_f(psh[nb][HID + j]);
            float gg = tanh_f(psh[nb][2 * HID + j]);
            float og = sigmoid_f(psh[nb][3 * HID + j]);
            c = fmaf(fg, c, ig * gg);
            zsh[((j >> 3) * 16 + nb) * 8 + (j & 7)] = (_Float16)(og * tanh_f(c));
        }
        __syncthreads();
    };

#pragma unroll 1
    for (int t = 0; t < TT; t += 2) {
        step(xgA0, xgA1, (t + 2 < TT) ? t + 2 : TT - 1);
        step(xgB0, xgB1, (t + 3 < TT) ? t + 3 : TT - 1);
    }

    if (tid < 20) {
        const int nb = tid / 10, k = tid - nb * 10;
        float s = fc_b[k];
        const float* w = fc_w + k * HID;
#pragma unroll
        for (int d = 0; d < HID; ++d)
            s = fmaf(w[d], (float)zsh[((d >> 3) * 16 + nb) * 8 + (d & 7)], s);
        out[(b0 + nb) * 10 + k] = s;
    }
}

// ============================================================================
// Fallback (round-4 kernel) if d_ws can't hold xg (268 MB).
// ============================================================================
#define KC7 7
#define ZSTR 232
__global__ __launch_bounds__(1024, 1) void lstm_mfma(
    const float* __restrict__ x, const float* __restrict__ w_ih,
    const float* __restrict__ w_hh, const float* __restrict__ b_ih,
    const float* __restrict__ b_hh, const float* __restrict__ fc_w,
    const float* __restrict__ fc_b, float* __restrict__ out)
{
    const int tid = threadIdx.x;
    const int wave = tid >> 6, lane = tid & 63;
    const int l15 = lane & 15, l4 = lane >> 4;
    const int b0 = blockIdx.x * 2;
    const int wb = wave * 32;

    __shared__ __align__(16) _Float16 zsh[16][ZSTR];
    __shared__ __align__(16) float    psh[2][512];

    {
        int* zi = (int*)&zsh[0][0];
        const int n4 = 16 * ZSTR / 2;
        for (int i = tid; i < n4; i += 1024) zi[i] = 0;
    }
    __syncthreads();
    if (tid >= 256 && tid < 256 + 2 * ISZ) {
        int u = tid - 256;
        int nb = (u >= ISZ) ? 1 : 0;
        int k = u - nb * ISZ;
        zsh[nb][HID + k] = (_Float16)x[((size_t)(b0 + nb) * TT) * ISZ + k];
    }
    half8 wfr[2][KC7];
    floatx4 bias[2];
#pragma unroll
    for (int mt = 0; mt < 2; ++mt) {
        const int R = wb + mt * 16 + l15;
#pragma unroll
        for (int kc = 0; kc < KC7; ++kc) {
            half8 f;
            const int kbase = kc * 32 + l4 * 8;
#pragma unroll
            for (int e = 0; e < 8; ++e) {
                const int k = kbase + e;
                float v = 0.f;
                if (k < HID)            v = w_hh[R * HID + k];
                else if (k < HID + ISZ) v = w_ih[R * ISZ + (k - HID)];
                f[e] = (_Float16)v;
            }
            wfr[mt][kc] = f;
        }
        floatx4 bf;
#pragma unroll
        for (int j = 0; j < 4; ++j) {
            const int g = wb + mt * 16 + l4 * 4 + j;
            bf[j] = b_ih[g] + b_hh[g];
        }
        bias[mt] = bf;
    }
    float c = 0.f;
    __syncthreads();
#pragma unroll 1
    for (int t = 0; t < TT; ++t) {
        float xpre = 0.f;
        int xnb = 0, xk = 0;
        const bool xthr = (tid >= 256 && tid < 256 + 2 * ISZ);
        if (xthr) {
            int u = tid - 256;
            xnb = (u >= ISZ) ? 1 : 0;
            xk = u - xnb * ISZ;
            int tn = (t + 1 < TT) ? (t + 1) : t;
            xpre = x[((size_t)(b0 + xnb) * TT + tn) * ISZ + xk];
        }
        floatx4 acc0 = bias[0], acc1 = bias[1];
#pragma unroll
        for (int kc = 0; kc < KC7; ++kc) {
            half8 z = *(const half8*)&zsh[l15][kc * 32 + l4 * 8];
            acc0 = __builtin_amdgcn_mfma_f32_16x16x32_f16(wfr[0][kc], z, acc0, 0, 0, 0);
            acc1 = __builtin_amdgcn_mfma_f32_16x16x32_f16(wfr[1][kc], z, acc1, 0, 0, 0);
        }
        if (l15 < 2) {
            *(floatx4*)&psh[l15][wb + l4 * 4]      = acc0;
            *(floatx4*)&psh[l15][wb + 16 + l4 * 4] = acc1;
        }
        __syncthreads();
        if (tid < 256) {
            const int nb = tid >> 7, j = tid & 127;
            float ig = sigmoid_f(psh[nb][j]);
            float fg = sigmoid_f(psh[nb][HID + j]);
            float gg = tanh_f(psh[nb][2 * HID + j]);
            float og = sigmoid_f(psh[nb][3 * HID + j]);
            c = fmaf(fg, c, ig * gg);
            zsh[nb][j] = (_Float16)(og * tanh_f(c));
        } else if (xthr && (t + 1 < TT)) {
            zsh[xnb][HID + xk] = (_Float16)xpre;
        }
        __syncthreads();
    }
    if (tid < 20) {
        const int nb = tid / 10, k = tid - nb * 10;
        float s = fc_b[k];
        const float* w = fc_w + k * HID;
#pragma unroll
        for (int d = 0; d < HID; ++d) s = fmaf(w[d], (float)zsh[nb][d], s);
        out[(b0 + nb) * 10 + k] = s;
    }
}

extern "C" void kernel_launch(void* const* d_in, const int* in_sizes, int n_in,
                              void* d_out, int out_size, void* d_ws, size_t ws_size,
                              hipStream_t stream) {
    const float* x    = (const float*)d_in[0];
    const float* w_ih = (const float*)d_in[1];
    const float* w_hh = (const float*)d_in[2];
    const float* b_ih = (const float*)d_in[3];
    const float* b_hh = (const float*)d_in[4];
    const float* fc_w = (const float*)d_in[5];
    const float* fc_b = (const float*)d_in[6];
    float* out = (float*)d_out;

    const size_t xg_bytes = (size_t)BB * TT * GATES * sizeof(_Float16);
    if (ws_size >= xg_bytes) {
        _Float16* xg = (_Float16*)d_ws;
        xg_gemm<<<dim3(512), dim3(256), 0, stream>>>(x, w_ih, b_ih, b_hh, xg);
        lstm_rec<<<dim3(BB / 2), dim3(1024), 0, stream>>>(xg, w_hh, fc_w, fc_b, out);
    } else {
        lstm_mfma<<<dim3(BB / 2), dim3(1024), 0, stream>>>(
            x, w_ih, w_hh, b_ih, b_hh, fc_w, fc_b, out);
    }
}